// Round 2
// baseline (14186.685 us; speedup 1.0000x reference)
//
#include <hip/hip_runtime.h>
#include <hip/hip_bf16.h>

#define SS 2048
#define EE 1024
#define FF 4096
#define HH 8
#define DD 128
#define LL 4
#define VV 32000

typedef short bf16x8 __attribute__((ext_vector_type(8)));
typedef float f32x4 __attribute__((ext_vector_type(4)));

static __device__ __forceinline__ short f2bf(float f) {
  unsigned u = __builtin_bit_cast(unsigned, f);
  u += 0x7fffu + ((u >> 16) & 1u);   // round-to-nearest-even
  return (short)(u >> 16);
}

// ---------------------------------------------------------------------------
// Embedding gather: h[s,e] = emb[x[s], e]   (all fp32)
// ---------------------------------------------------------------------------
__global__ void embed_kernel(const int* __restrict__ x,
                             const float* __restrict__ emb,
                             float* __restrict__ h) {
  const int s = blockIdx.x;
  const int row = x[s];
  const float* src = emb + (long)row * EE;
  float* dst = h + (long)s * EE;
  for (int e = threadIdx.x; e < EE; e += blockDim.x)
    dst[e] = src[e];
}

// ---------------------------------------------------------------------------
// MFMA bf16 GEMM: C[M,N] = A[M,K] x B  (A,B fp32 in HBM, rounded to bf16 in
// LDS staging; fp32 accumulate).  BLAYOUT==0: B is [N,K] (NT); ==1: [K,N].
// 128x128 tile, BK=32, 256 threads = 4 waves (2x2), each wave 64x64 via
// 4x4 v_mfma_f32_16x16x32_bf16.
// ---------------------------------------------------------------------------
template <int BLAYOUT, int RELU>
__global__ __launch_bounds__(256) void gemm_kernel(
    const float* __restrict__ A, const float* __restrict__ B,
    float* __restrict__ C, int M, int N, int K) {
  __shared__ __align__(16) short As[128][32];
  __shared__ __align__(16) short Bs[128][32];  // [n][k]

  const int tid = threadIdx.x;
  const long bm = (long)blockIdx.y * 128;
  const long bn = (long)blockIdx.x * 128;
  const int wave = tid >> 6;
  const int lane = tid & 63;
  const int wm = (wave >> 1) * 64;
  const int wn = (wave & 1) * 64;
  const int lr = lane & 15;    // row (A) / col (B,C)
  const int quad = lane >> 4;  // 0..3

  f32x4 acc[4][4] = {};

  for (int k0 = 0; k0 < K; k0 += 32) {
    // ---- stage A: fp32 -> bf16, [128][32]
    {
      const int chunk = tid & 7;   // 4-float k-chunk
      const int r0 = tid >> 3;     // 0..31
#pragma unroll
      for (int rr = 0; rr < 4; rr++) {
        const int r = r0 + rr * 32;
        const float4 va =
            *reinterpret_cast<const float4*>(A + (bm + r) * (long)K + k0 + chunk * 4);
        short* dst = &As[r][chunk * 4];
        dst[0] = f2bf(va.x);
        dst[1] = f2bf(va.y);
        dst[2] = f2bf(va.z);
        dst[3] = f2bf(va.w);
      }
    }
    // ---- stage B: fp32 -> bf16
    if (BLAYOUT == 0) {  // NT: B[N,K]
      const int chunk = tid & 7;   // k-chunk of 4
      const int r0 = tid >> 3;     // 0..31
#pragma unroll
      for (int rr = 0; rr < 4; rr++) {
        const int r = r0 + rr * 32;
        const float4 vb =
            *reinterpret_cast<const float4*>(B + (bn + r) * (long)K + k0 + chunk * 4);
        short* dst = &Bs[r][chunk * 4];
        dst[0] = f2bf(vb.x);
        dst[1] = f2bf(vb.y);
        dst[2] = f2bf(vb.z);
        dst[3] = f2bf(vb.w);
      }
    } else {  // NN: B[K,N] -> transpose-scatter into [n][k]
      const int chunk = tid & 31;  // n-chunk of 4 (128 cols)
      const int kr0 = tid >> 5;    // 0..7
#pragma unroll
      for (int rr = 0; rr < 4; rr++) {
        const int kr = kr0 + rr * 8;
        const float4 vb =
            *reinterpret_cast<const float4*>(B + (long)(k0 + kr) * N + bn + chunk * 4);
        Bs[chunk * 4 + 0][kr] = f2bf(vb.x);
        Bs[chunk * 4 + 1][kr] = f2bf(vb.y);
        Bs[chunk * 4 + 2][kr] = f2bf(vb.z);
        Bs[chunk * 4 + 3][kr] = f2bf(vb.w);
      }
    }
    __syncthreads();

    bf16x8 af[4], bfr[4];
#pragma unroll
    for (int mi = 0; mi < 4; mi++)
      af[mi] = *reinterpret_cast<const bf16x8*>(&As[wm + mi * 16 + lr][quad * 8]);
#pragma unroll
    for (int ni = 0; ni < 4; ni++)
      bfr[ni] = *reinterpret_cast<const bf16x8*>(&Bs[wn + ni * 16 + lr][quad * 8]);
#pragma unroll
    for (int mi = 0; mi < 4; mi++)
#pragma unroll
      for (int ni = 0; ni < 4; ni++)
        acc[mi][ni] = __builtin_amdgcn_mfma_f32_16x16x32_bf16(af[mi], bfr[ni],
                                                              acc[mi][ni], 0, 0, 0);
    __syncthreads();
  }

  // ---- epilogue; C/D layout: col = lane&15, row = quad*4 + reg
#pragma unroll
  for (int mi = 0; mi < 4; mi++) {
#pragma unroll
    for (int ni = 0; ni < 4; ni++) {
#pragma unroll
      for (int r = 0; r < 4; r++) {
        const long row = bm + wm + mi * 16 + quad * 4 + r;
        const long col = bn + wn + ni * 16 + lr;
        float v = acc[mi][ni][r];
        if (RELU) v = fmaxf(v, 0.0f);
        C[row * (long)N + col] = v;
      }
    }
  }
}

// ---------------------------------------------------------------------------
// Causal attention, fp32, one block per (query row s, head h).
// No 1/sqrt(D) scale (reference has none). Scores staged in LDS.
// ---------------------------------------------------------------------------
__global__ __launch_bounds__(256) void attn_kernel(const float* __restrict__ q,
                                                   const float* __restrict__ k,
                                                   const float* __restrict__ v,
                                                   float* __restrict__ o) {
  __shared__ float qs[DD];
  __shared__ float sc[SS];
  __shared__ float red[16];
  __shared__ float pvb[2][DD];

  const int s = blockIdx.x;
  const int h = blockIdx.y;
  const int tid = threadIdx.x;
  const int lane = tid & 63;
  const int wid = tid >> 6;

  const float* Q = q + (long)s * (HH * DD) + h * DD;
  if (tid < DD) qs[tid] = Q[tid];
  __syncthreads();

  // scores
  float lmax = -3.0e38f;
  for (int t = tid; t <= s; t += 256) {
    const float* Kr = k + (long)t * (HH * DD) + h * DD;
    float acc = 0.f;
#pragma unroll
    for (int d0 = 0; d0 < DD; d0 += 4) {
      float4 kv = *reinterpret_cast<const float4*>(Kr + d0);
      acc += qs[d0] * kv.x + qs[d0 + 1] * kv.y + qs[d0 + 2] * kv.z +
             qs[d0 + 3] * kv.w;
    }
    sc[t] = acc;
    lmax = fmaxf(lmax, acc);
  }
  // block-reduce max
#pragma unroll
  for (int off = 32; off > 0; off >>= 1) lmax = fmaxf(lmax, __shfl_down(lmax, off));
  if (lane == 0) red[wid] = lmax;
  __syncthreads();
  if (tid == 0) {
    float m = red[0];
    for (int i = 1; i < 4; i++) m = fmaxf(m, red[i]);
    red[8] = m;
  }
  __syncthreads();
  const float m = red[8];

  // exp + sum
  float lsum = 0.f;
  for (int t = tid; t <= s; t += 256) {
    float p = __expf(sc[t] - m);
    sc[t] = p;
    lsum += p;
  }
  __syncthreads();  // sc fully written before PV
#pragma unroll
  for (int off = 32; off > 0; off >>= 1) lsum += __shfl_down(lsum, off);
  if (lane == 0) red[wid] = lsum;
  __syncthreads();
  if (tid == 0) red[8] = red[0] + red[1] + red[2] + red[3];
  __syncthreads();
  const float inv_l = 1.0f / red[8];

  // PV: thread d accumulates over t (2-way t split)
  const int d = tid & (DD - 1);
  const int half = tid >> 7;
  float acc = 0.f;
  for (int t = half; t <= s; t += 2)
    acc += sc[t] * v[(long)t * (HH * DD) + h * DD + d];
  pvb[half][d] = acc;
  __syncthreads();
  if (tid < DD)
    o[(long)s * (HH * DD) + h * DD + tid] = (pvb[0][tid] + pvb[1][tid]) * inv_l;
}

// ---------------------------------------------------------------------------
extern "C" void kernel_launch(void* const* d_in, const int* in_sizes, int n_in,
                              void* d_out, int out_size, void* d_ws, size_t ws_size,
                              hipStream_t stream) {
  const int* x = (const int*)d_in[0];
  const float* emb = (const float*)d_in[1];
  const float* ff_w = (const float*)d_in[2];
  const float* q_w = (const float*)d_in[3];
  const float* k_w = (const float*)d_in[4];
  const float* v_w = (const float*)d_in[5];
  const float* o_w = (const float*)d_in[6];

  // workspace layout (fp32): h | hf | q | k | v ; o aliases hf  = 64 MB
  float* ws = (float*)d_ws;
  float* h = ws;
  float* hf = h + (size_t)SS * EE;
  float* q = hf + (size_t)SS * FF;
  float* k = q + (size_t)SS * EE;
  float* v = k + (size_t)SS * EE;
  float* o = hf;  // hf is dead after the V projection

  embed_kernel<<<SS, 256, 0, stream>>>(x, emb, h);

  for (int i = 0; i < LL; i++) {
    // hf = relu(h @ ff_w[i])   [2048,1024]x[1024,4096]
    gemm_kernel<1, 1><<<dim3(FF / 128, SS / 128), 256, 0, stream>>>(
        h, ff_w + (size_t)i * EE * FF, hf, SS, FF, EE);
    // q/k/v = hf @ {q,k,v}_w[i]   [2048,4096]x[4096,1024]
    gemm_kernel<1, 0><<<dim3(EE / 128, SS / 128), 256, 0, stream>>>(
        hf, q_w + (size_t)i * FF * EE, q, SS, EE, FF);
    gemm_kernel<1, 0><<<dim3(EE / 128, SS / 128), 256, 0, stream>>>(
        hf, k_w + (size_t)i * FF * EE, k, SS, EE, FF);
    gemm_kernel<1, 0><<<dim3(EE / 128, SS / 128), 256, 0, stream>>>(
        hf, v_w + (size_t)i * FF * EE, v, SS, EE, FF);
    // causal attention (writes o = hf region; hf dead from here)
    attn_kernel<<<dim3(SS, HH), 256, 0, stream>>>(q, k, v, o);
    // h = o @ o_w[i]   [2048,1024]x[1024,1024]
    gemm_kernel<1, 0><<<dim3(EE / 128, SS / 128), 256, 0, stream>>>(
        o, o_w + (size_t)i * EE * EE, h, SS, EE, EE);
  }

  // logits = h @ emb^T  (NT: emb is [V,E]), fp32 out
  gemm_kernel<0, 0><<<dim3(VV / 128, SS / 128), 256, 0, stream>>>(
      h, emb, (float*)d_out, SS, VV, EE);
}